// Round 1
// baseline (1497.802 us; speedup 1.0000x reference)
//
#include <hip/hip_runtime.h>
#include <stdint.h>

#define TSIZE (1u << 19)
#define TMASK (TSIZE - 1u)

// grid_size = 2/res, fp32 correctly-rounded (compile-time folded), matching
// the reference's fp32 division. Resolutions: floor(16 * b^l), b = 32^(1/15);
// fp32 b rounds ~3 ulps above 2^(1/3) so the pow-of-2 levels are 32/64/.../512.
static __device__ const float GS_F[16] = {
    2.0f/16.0f, 2.0f/20.0f, 2.0f/25.0f, 2.0f/32.0f,
    2.0f/40.0f, 2.0f/50.0f, 2.0f/64.0f, 2.0f/80.0f,
    2.0f/101.0f, 2.0f/128.0f, 2.0f/161.0f, 2.0f/203.0f,
    2.0f/256.0f, 2.0f/322.0f, 2.0f/406.0f, 2.0f/512.0f};
// res/2 — exact in fp32.
static __device__ const float INVGS_F[16] = {
    8.0f, 10.0f, 12.5f, 16.0f,
    20.0f, 25.0f, 32.0f, 40.0f,
    50.5f, 64.0f, 80.5f, 101.5f,
    128.0f, 161.0f, 203.0f, 256.0f};

__global__ __launch_bounds__(256) void hashenc_kernel(
    const float* __restrict__ x,
    const float* __restrict__ emb,
    float* __restrict__ out,
    int B)
{
    const int b = blockIdx.x * blockDim.x + threadIdx.x;
    if (b >= B) return;

    const float cx = fminf(fmaxf(x[3*b+0], -1.0f), 1.0f);
    const float cy = fminf(fmaxf(x[3*b+1], -1.0f), 1.0f);
    const float cz = fminf(fmaxf(x[3*b+2], -1.0f), 1.0f);

#pragma unroll 1
    for (int l = 0; l < 16; ++l) {
        const float gs  = GS_F[l];
        const float ivg = INVGS_F[l];

        const float ux = (cx + 1.0f) * ivg;
        const float uy = (cy + 1.0f) * ivg;
        const float uz = (cz + 1.0f) * ivg;
        const float fx = floorf(ux), fy = floorf(uy), fz = floorf(uz);
        const int ix = (int)fx, iy = (int)fy, iz = (int)fz;
        // w = (xc - (bl*gs + BOX_MIN)) / gs  — continuity makes ulp-level
        // floor disagreements with the reference benign.
        const float wx = (cx - (fx * gs - 1.0f)) * ivg;
        const float wy = (cy - (fy * gs - 1.0f)) * ivg;
        const float wz = (cz - (fz * gs - 1.0f)) * ivg;

        // int32-wraparound hash, primes per dim (x,y,z order)
        const uint32_t px0 = (uint32_t)ix * 73856093u;
        const uint32_t px1 = px0 + 73856093u;
        const uint32_t py0 = (uint32_t)iy * 19349663u;
        const uint32_t py1 = py0 + 19349663u;
        const uint32_t pz0 = (uint32_t)iz * 83492791u;
        const uint32_t pz1 = pz0 + 83492791u;

        const float2* __restrict__ tb = ((const float2*)emb) + ((size_t)l << 19);

        // 8 independent gathers issued together for memory-level parallelism
        const float2 e000 = tb[(px0 ^ py0 ^ pz0) & TMASK];
        const float2 e001 = tb[(px0 ^ py0 ^ pz1) & TMASK];
        const float2 e010 = tb[(px0 ^ py1 ^ pz0) & TMASK];
        const float2 e011 = tb[(px0 ^ py1 ^ pz1) & TMASK];
        const float2 e100 = tb[(px1 ^ py0 ^ pz0) & TMASK];
        const float2 e101 = tb[(px1 ^ py0 ^ pz1) & TMASK];
        const float2 e110 = tb[(px1 ^ py1 ^ pz0) & TMASK];
        const float2 e111 = tb[(px1 ^ py1 ^ pz1) & TMASK];

        const float wx0 = 1.0f - wx, wy0 = 1.0f - wy, wz0 = 1.0f - wz;
        const float c00 = wx0 * wy0, c01 = wx0 * wy;
        const float c10 = wx  * wy0, c11 = wx  * wy;
        const float w000 = c00 * wz0, w001 = c00 * wz;
        const float w010 = c01 * wz0, w011 = c01 * wz;
        const float w100 = c10 * wz0, w101 = c10 * wz;
        const float w110 = c11 * wz0, w111 = c11 * wz;

        const float o0 = w000 * e000.x + w001 * e001.x + w010 * e010.x + w011 * e011.x
                       + w100 * e100.x + w101 * e101.x + w110 * e110.x + w111 * e111.x;
        const float o1 = w000 * e000.y + w001 * e001.y + w010 * e010.y + w011 * e011.y
                       + w100 * e100.y + w101 * e101.y + w110 * e110.y + w111 * e111.y;

        *(float2*)(out + (size_t)b * 32 + l * 2) = make_float2(o0, o1);
    }
}

extern "C" void kernel_launch(void* const* d_in, const int* in_sizes, int n_in,
                              void* d_out, int out_size, void* d_ws, size_t ws_size,
                              hipStream_t stream) {
    const float* x   = (const float*)d_in[0];
    const float* emb = (const float*)d_in[1];
    float* out = (float*)d_out;
    const int B = in_sizes[0] / 3;
    const int grid = (B + 255) / 256;
    hashenc_kernel<<<grid, 256, 0, stream>>>(x, emb, out, B);
}

// Round 2
// 1143.732 us; speedup vs baseline: 1.3096x; 1.3096x over previous
//
#include <hip/hip_runtime.h>
#include <stdint.h>

#define TMASK ((1u << 19) - 1u)

typedef float vf2 __attribute__((ext_vector_type(2)));
typedef float vf4 __attribute__((ext_vector_type(4)));

// grid_size = 2/res, fp32 correctly-rounded (compile-time folded), matching
// the reference's fp32 division. Resolutions: floor(16 * b^l), b = 32^(1/15);
// fp32 b rounds ~3 ulps above 2^(1/3) so the pow-of-2 levels are 32/64/.../512.
static __device__ const float GS_F[16] = {
    2.0f/16.0f, 2.0f/20.0f, 2.0f/25.0f, 2.0f/32.0f,
    2.0f/40.0f, 2.0f/50.0f, 2.0f/64.0f, 2.0f/80.0f,
    2.0f/101.0f, 2.0f/128.0f, 2.0f/161.0f, 2.0f/203.0f,
    2.0f/256.0f, 2.0f/322.0f, 2.0f/406.0f, 2.0f/512.0f};
// res/2 — exact in fp32.
static __device__ const float INVGS_F[16] = {
    8.0f, 10.0f, 12.5f, 16.0f,
    20.0f, 25.0f, 32.0f, 40.0f,
    50.5f, 64.0f, 80.5f, 101.5f,
    128.0f, 161.0f, 203.0f, 256.0f};

// Processes levels [l0, l1] for one point per thread.
// dst index = l*lstride + b*bstride:
//   two-pass:  lstride=B, bstride=1  (level-major ws, coalesced full lines)
//   fallback:  lstride=1, bstride=16 (direct scatter into out)
__global__ __launch_bounds__(256) void level_kernel(
    const float* __restrict__ x,
    const float* __restrict__ emb,
    vf2* __restrict__ dst,
    long lstride, long bstride,
    int B, int l0, int l1)
{
    const int b = blockIdx.x * blockDim.x + threadIdx.x;
    if (b >= B) return;

    const float cx = fminf(fmaxf(x[3*b+0], -1.0f), 1.0f);
    const float cy = fminf(fmaxf(x[3*b+1], -1.0f), 1.0f);
    const float cz = fminf(fmaxf(x[3*b+2], -1.0f), 1.0f);

#pragma unroll 1
    for (int l = l0; l <= l1; ++l) {
        const float gs  = GS_F[l];
        const float ivg = INVGS_F[l];

        const float ux = (cx + 1.0f) * ivg;
        const float uy = (cy + 1.0f) * ivg;
        const float uz = (cz + 1.0f) * ivg;
        const float fx = floorf(ux), fy = floorf(uy), fz = floorf(uz);
        const int ix = (int)fx, iy = (int)fy, iz = (int)fz;
        // w = (xc - (bl*gs + BOX_MIN)) / gs — interpolation is continuous, so
        // ulp-level floor disagreements with the reference are benign.
        const float wx = (cx - (fx * gs - 1.0f)) * ivg;
        const float wy = (cy - (fy * gs - 1.0f)) * ivg;
        const float wz = (cz - (fz * gs - 1.0f)) * ivg;

        // int32-wraparound hash, primes per dim (x,y,z order)
        const uint32_t px0 = (uint32_t)ix * 73856093u;
        const uint32_t px1 = px0 + 73856093u;
        const uint32_t py0 = (uint32_t)iy * 19349663u;
        const uint32_t py1 = py0 + 19349663u;
        const uint32_t pz0 = (uint32_t)iz * 83492791u;
        const uint32_t pz1 = pz0 + 83492791u;

        const vf2* __restrict__ tb = ((const vf2*)emb) + ((size_t)l << 19);

        // 8 independent gathers issued together for memory-level parallelism;
        // single-level dispatch keeps this level's 4 MB slice L2-resident.
        const vf2 e000 = tb[(px0 ^ py0 ^ pz0) & TMASK];
        const vf2 e001 = tb[(px0 ^ py0 ^ pz1) & TMASK];
        const vf2 e010 = tb[(px0 ^ py1 ^ pz0) & TMASK];
        const vf2 e011 = tb[(px0 ^ py1 ^ pz1) & TMASK];
        const vf2 e100 = tb[(px1 ^ py0 ^ pz0) & TMASK];
        const vf2 e101 = tb[(px1 ^ py0 ^ pz1) & TMASK];
        const vf2 e110 = tb[(px1 ^ py1 ^ pz0) & TMASK];
        const vf2 e111 = tb[(px1 ^ py1 ^ pz1) & TMASK];

        const float wxm = 1.0f - wx, wym = 1.0f - wy, wzm = 1.0f - wz;
        const float c00 = wxm * wym, c01 = wxm * wy;
        const float c10 = wx  * wym, c11 = wx  * wy;
        const float w000 = c00 * wzm, w001 = c00 * wz;
        const float w010 = c01 * wzm, w011 = c01 * wz;
        const float w100 = c10 * wzm, w101 = c10 * wz;
        const float w110 = c11 * wzm, w111 = c11 * wz;

        vf2 r;
        r.x = w000 * e000.x + w001 * e001.x + w010 * e010.x + w011 * e011.x
            + w100 * e100.x + w101 * e101.x + w110 * e110.x + w111 * e111.x;
        r.y = w000 * e000.y + w001 * e001.y + w010 * e010.y + w011 * e011.y
            + w100 * e100.y + w101 * e101.y + w110 * e110.y + w111 * e111.y;

        // Nontemporal: don't let streaming result-writes evict the table.
        __builtin_nontemporal_store(r, &dst[(long)l * lstride + (long)b * bstride]);
    }
}

// ws [L][B] float2  ->  out [B][L] float2. Reads coalesced per level
// (lane-consecutive b), writes each point's 128 B as 8 float4.
__global__ __launch_bounds__(256) void transpose_kernel(
    const vf2* __restrict__ ws, vf4* __restrict__ out, int B)
{
    const int b = blockIdx.x * blockDim.x + threadIdx.x;
    if (b >= B) return;
    vf2 v[16];
#pragma unroll
    for (int l = 0; l < 16; ++l)
        v[l] = __builtin_nontemporal_load(&ws[(long)l * B + b]);
#pragma unroll
    for (int j = 0; j < 8; ++j) {
        vf4 t;
        t.x = v[2*j].x; t.y = v[2*j].y; t.z = v[2*j+1].x; t.w = v[2*j+1].y;
        __builtin_nontemporal_store(t, &out[(long)b * 8 + j]);
    }
}

extern "C" void kernel_launch(void* const* d_in, const int* in_sizes, int n_in,
                              void* d_out, int out_size, void* d_ws, size_t ws_size,
                              hipStream_t stream) {
    const float* x   = (const float*)d_in[0];
    const float* emb = (const float*)d_in[1];
    const int B = in_sizes[0] / 3;
    const int grid = (B + 255) / 256;

    const bool two_pass = ws_size >= (size_t)B * 16 * sizeof(vf2);

    if (two_pass) {
        vf2* ws = (vf2*)d_ws;
        // Levels 0-5: combined corner working set ~2 MB -> one fused launch.
        level_kernel<<<grid, 256, 0, stream>>>(x, emb, ws, (long)B, 1L, B, 0, 5);
        // Fine levels: one launch each so the 4 MB slice owns each XCD's L2.
        for (int l = 6; l < 16; ++l)
            level_kernel<<<grid, 256, 0, stream>>>(x, emb, ws, (long)B, 1L, B, l, l);
        transpose_kernel<<<grid, 256, 0, stream>>>(ws, (vf4*)d_out, B);
    } else {
        // Fallback: scatter directly into out (correct, more write traffic).
        vf2* o = (vf2*)d_out;
        level_kernel<<<grid, 256, 0, stream>>>(x, emb, o, 1L, 16L, B, 0, 5);
        for (int l = 6; l < 16; ++l)
            level_kernel<<<grid, 256, 0, stream>>>(x, emb, o, 1L, 16L, B, l, l);
    }
}

// Round 3
// 827.528 us; speedup vs baseline: 1.8100x; 1.3821x over previous
//
#include <hip/hip_runtime.h>
#include <stdint.h>

#define TMASK ((1u << 19) - 1u)

typedef float vf2 __attribute__((ext_vector_type(2)));
typedef float vf4 __attribute__((ext_vector_type(4)));

// grid_size = 2/res, fp32 correctly-rounded (compile-time folded), matching
// the reference's fp32 division. Resolutions: floor(16 * b^l), b = 32^(1/15);
// fp32 b rounds ~3 ulps above 2^(1/3) so the pow-of-2 levels are 32/64/.../512.
static __device__ const float GS_F[16] = {
    2.0f/16.0f, 2.0f/20.0f, 2.0f/25.0f, 2.0f/32.0f,
    2.0f/40.0f, 2.0f/50.0f, 2.0f/64.0f, 2.0f/80.0f,
    2.0f/101.0f, 2.0f/128.0f, 2.0f/161.0f, 2.0f/203.0f,
    2.0f/256.0f, 2.0f/322.0f, 2.0f/406.0f, 2.0f/512.0f};
// res/2 — exact in fp32.
static __device__ const float INVGS_F[16] = {
    8.0f, 10.0f, 12.5f, 16.0f,
    20.0f, 25.0f, 32.0f, 40.0f,
    50.5f, 64.0f, 80.5f, 101.5f,
    128.0f, 161.0f, 203.0f, 256.0f};

struct Corner8 { vf2 e[8]; float w[8]; };

__device__ __forceinline__ void gather_level(
    const vf2* __restrict__ tb, float cx, float cy, float cz,
    float gs, float ivg, Corner8& g)
{
    const float ux = (cx + 1.0f) * ivg;
    const float uy = (cy + 1.0f) * ivg;
    const float uz = (cz + 1.0f) * ivg;
    const float fx = floorf(ux), fy = floorf(uy), fz = floorf(uz);
    const int ix = (int)fx, iy = (int)fy, iz = (int)fz;
    const float wx = (cx - (fx * gs - 1.0f)) * ivg;
    const float wy = (cy - (fy * gs - 1.0f)) * ivg;
    const float wz = (cz - (fz * gs - 1.0f)) * ivg;

    const uint32_t px0 = (uint32_t)ix * 73856093u, px1 = px0 + 73856093u;
    const uint32_t py0 = (uint32_t)iy * 19349663u, py1 = py0 + 19349663u;
    const uint32_t pz0 = (uint32_t)iz * 83492791u, pz1 = pz0 + 83492791u;

    g.e[0] = tb[(px0 ^ py0 ^ pz0) & TMASK];
    g.e[1] = tb[(px0 ^ py0 ^ pz1) & TMASK];
    g.e[2] = tb[(px0 ^ py1 ^ pz0) & TMASK];
    g.e[3] = tb[(px0 ^ py1 ^ pz1) & TMASK];
    g.e[4] = tb[(px1 ^ py0 ^ pz0) & TMASK];
    g.e[5] = tb[(px1 ^ py0 ^ pz1) & TMASK];
    g.e[6] = tb[(px1 ^ py1 ^ pz0) & TMASK];
    g.e[7] = tb[(px1 ^ py1 ^ pz1) & TMASK];

    const float wxm = 1.0f - wx, wym = 1.0f - wy, wzm = 1.0f - wz;
    const float c00 = wxm * wym, c01 = wxm * wy;
    const float c10 = wx  * wym, c11 = wx  * wy;
    g.w[0] = c00 * wzm; g.w[1] = c00 * wz;
    g.w[2] = c01 * wzm; g.w[3] = c01 * wz;
    g.w[4] = c10 * wzm; g.w[5] = c10 * wz;
    g.w[6] = c11 * wzm; g.w[7] = c11 * wz;
}

__device__ __forceinline__ vf2 blend(const Corner8& g) {
    vf2 r;
    r.x = g.w[0]*g.e[0].x + g.w[1]*g.e[1].x + g.w[2]*g.e[2].x + g.w[3]*g.e[3].x
        + g.w[4]*g.e[4].x + g.w[5]*g.e[5].x + g.w[6]*g.e[6].x + g.w[7]*g.e[7].x;
    r.y = g.w[0]*g.e[0].y + g.w[1]*g.e[1].y + g.w[2]*g.e[2].y + g.w[3]*g.e[3].y
        + g.w[4]*g.e[4].y + g.w[5]*g.e[5].y + g.w[6]*g.e[6].y + g.w[7]*g.e[7].y;
    return r;
}

// Two points per thread (split-half so both are lane-coalesced): 16
// outstanding divergent gathers per wave iteration for latency hiding.
// ws layout: [l][b] float2 (level-major, coalesced full-line stores).
__global__ __launch_bounds__(256) void level_kernel(
    const float* __restrict__ x,
    const float* __restrict__ emb,
    vf2* __restrict__ ws,
    int B, int half, int l0, int l1)
{
    const int p0 = blockIdx.x * blockDim.x + threadIdx.x;
    if (p0 >= half) return;
    const int p1 = p0 + half;
    const bool has1 = p1 < B;
    const int p1c = has1 ? p1 : p0;

    // Nontemporal: streaming x must not evict the L2-resident table slice.
    const float ax = __builtin_nontemporal_load(x + 3*p0 + 0);
    const float ay = __builtin_nontemporal_load(x + 3*p0 + 1);
    const float az = __builtin_nontemporal_load(x + 3*p0 + 2);
    const float bx = __builtin_nontemporal_load(x + 3*p1c + 0);
    const float by = __builtin_nontemporal_load(x + 3*p1c + 1);
    const float bz = __builtin_nontemporal_load(x + 3*p1c + 2);

    const float cax = fminf(fmaxf(ax, -1.0f), 1.0f);
    const float cay = fminf(fmaxf(ay, -1.0f), 1.0f);
    const float caz = fminf(fmaxf(az, -1.0f), 1.0f);
    const float cbx = fminf(fmaxf(bx, -1.0f), 1.0f);
    const float cby = fminf(fmaxf(by, -1.0f), 1.0f);
    const float cbz = fminf(fmaxf(bz, -1.0f), 1.0f);

#pragma unroll 1
    for (int l = l0; l <= l1; ++l) {
        const float gs  = GS_F[l];
        const float ivg = INVGS_F[l];
        const vf2* __restrict__ tb = ((const vf2*)emb) + ((size_t)l << 19);

        Corner8 ga, gb;
        gather_level(tb, cax, cay, caz, gs, ivg, ga);
        gather_level(tb, cbx, cby, cbz, gs, ivg, gb);

        const vf2 ra = blend(ga);
        const vf2 rb = blend(gb);

        __builtin_nontemporal_store(ra, &ws[(long)l * B + p0]);
        if (has1) __builtin_nontemporal_store(rb, &ws[(long)l * B + p1]);
    }
}

// ws [16][B] float2 -> out [B][8] float4, LDS-tiled so global writes are
// lane-consecutive float4s (full 64B lines per wave store).
__global__ __launch_bounds__(256) void transpose_kernel(
    const vf2* __restrict__ ws, vf4* __restrict__ out, int B)
{
    __shared__ vf2 tile[16][257];   // +1 pad: store-phase reads drop to <=2-way
    const int t = threadIdx.x;
    const int base = blockIdx.x * 256;

#pragma unroll
    for (int l = 0; l < 16; ++l) {
        const int b = base + t;
        if (b < B) tile[l][t] = __builtin_nontemporal_load(&ws[(long)l * B + b]);
    }
    __syncthreads();

#pragma unroll
    for (int k = 0; k < 8; ++k) {
        const int flat = k * 256 + t;        // float4 index within block's 2048
        const int p = flat >> 3;             // local point
        const int j = flat & 7;              // float4 slot within point
        if (base + p < B) {
            const vf2 a = tile[2*j][p];
            const vf2 c = tile[2*j+1][p];
            vf4 v; v.x = a.x; v.y = a.y; v.z = c.x; v.w = c.y;
            __builtin_nontemporal_store(v, &out[(long)base * 8 + flat]);
        }
    }
}

// Fallback (ws too small): direct scatter, one point per thread.
__global__ __launch_bounds__(256) void level_scatter_kernel(
    const float* __restrict__ x,
    const float* __restrict__ emb,
    vf2* __restrict__ out,
    int B, int l0, int l1)
{
    const int b = blockIdx.x * blockDim.x + threadIdx.x;
    if (b >= B) return;
    const float cx = fminf(fmaxf(x[3*b+0], -1.0f), 1.0f);
    const float cy = fminf(fmaxf(x[3*b+1], -1.0f), 1.0f);
    const float cz = fminf(fmaxf(x[3*b+2], -1.0f), 1.0f);
#pragma unroll 1
    for (int l = l0; l <= l1; ++l) {
        const vf2* __restrict__ tb = ((const vf2*)emb) + ((size_t)l << 19);
        Corner8 g;
        gather_level(tb, cx, cy, cz, GS_F[l], INVGS_F[l], g);
        out[(long)b * 16 + l] = blend(g);
    }
}

extern "C" void kernel_launch(void* const* d_in, const int* in_sizes, int n_in,
                              void* d_out, int out_size, void* d_ws, size_t ws_size,
                              hipStream_t stream) {
    const float* x   = (const float*)d_in[0];
    const float* emb = (const float*)d_in[1];
    const int B = in_sizes[0] / 3;

    if (ws_size >= (size_t)B * 16 * sizeof(vf2)) {
        vf2* ws = (vf2*)d_ws;
        const int half = (B + 1) / 2;
        const int grid = (half + 255) / 256;
        // Levels 0-5: combined corner working set ~2 MB -> one fused launch.
        level_kernel<<<grid, 256, 0, stream>>>(x, emb, ws, B, half, 0, 5);
        // Fine levels: one launch each so the 4 MB slice owns each XCD's L2.
        for (int l = 6; l < 16; ++l)
            level_kernel<<<grid, 256, 0, stream>>>(x, emb, ws, B, half, l, l);
        transpose_kernel<<<(B + 255) / 256, 256, 0, stream>>>(ws, (vf4*)d_out, B);
    } else {
        const int grid = (B + 255) / 256;
        vf2* o = (vf2*)d_out;
        level_scatter_kernel<<<grid, 256, 0, stream>>>(x, emb, o, B, 0, 5);
        for (int l = 6; l < 16; ++l)
            level_scatter_kernel<<<grid, 256, 0, stream>>>(x, emb, o, B, l, l);
    }
}